// Round 7
// baseline (76.661 us; speedup 1.0000x reference)
//
#include <hip/hip_runtime.h>
#include <hip/hip_bf16.h>

// HarmonicOscillatorOrbitals: out[b,i,j] = exp(-s^2/2) * H_j(s), s = x[b,i]*k
// x: (65536, 32, 1) fp32; out: (65536, 32, 32) fp32 (= 16,777,216 float4 slots).
//
// Layout (unchanged from round 6, byte-identical store pattern):
//   slot f = blockIdx.x*2048 + kk*256 + tid, row = f>>3, quad = tid&7.
//   Every store instruction is wave-contiguous (1 KB/wave-store).
// Changes this round (pure issue/VALU cuts, memory pattern identical):
//   1. GUARD templated out: n_quads % 2048 == 0 here, so bulk blocks carry
//      zero bounds compares/branches on the store path.
//   2. Per-chain restructure: each chain advances AND stores before the next,
//      so store kk can issue while chains kk+1.. still compute (was: all 8
//      chains in one lockstep loop, all stores gated on the slowest).
//   3. __expf -> direct v_exp_f32 path (tolerance is ~bf16-level, huge).

#define KPT 8  // float4 slots per thread

typedef float f32x4 __attribute__((ext_vector_type(4)));

template <bool GUARD>
__global__ __launch_bounds__(256) void hoo_kernel(
    const float* __restrict__ x,
    const float* __restrict__ omega,
    f32x4* __restrict__ out4,
    unsigned n_quads)
{
    const unsigned tid  = threadIdx.x;
    const unsigned quad = tid & 7;  // same for all KPT slots (256 % 8 == 0)
    const unsigned base = blockIdx.x * (256u * KPT) + tid;

    const float k = omega[0];

#pragma unroll
    for (int kk = 0; kk < KPT; ++kk) {
        const unsigned f = base + (unsigned)kk * 256u;
        if (GUARD && f >= n_quads) continue;
        const unsigned row = f >> 3;

        const float s  = x[row] * k;
        const float env = __expf(-0.5f * (s * s));
        const float tx = 2.0f * s;

        // H_0=1, H_1=2x, H_k = 2x*H_{k-1} - 2(k-1)*H_{k-2}
        float h0 = 1.0f;
        float h1 = tx;
        float h2 = tx * h1 - 2.0f;
        float h3 = tx * h2 - 4.0f * h1;

        float c = 6.0f;  // 2*(k-1) for k=4
        for (unsigned it = 0; it < quad; ++it) {
            const float n0 = tx * h3 - c          * h2;
            const float n1 = tx * n0 - (c + 2.0f) * h3;
            const float n2 = tx * n1 - (c + 4.0f) * n0;
            const float n3 = tx * n2 - (c + 6.0f) * n1;
            h0 = n0; h1 = n1; h2 = n2; h3 = n3;
            c += 8.0f;
        }

        f32x4 v;
        v.x = env * h0;
        v.y = env * h1;
        v.z = env * h2;
        v.w = env * h3;
        out4[f] = v;  // store issues as soon as THIS chain is done
    }
}

extern "C" void kernel_launch(void* const* d_in, const int* in_sizes, int n_in,
                              void* d_out, int out_size, void* d_ws, size_t ws_size,
                              hipStream_t stream) {
    const float* x     = (const float*)d_in[0];
    const float* omega = (const float*)d_in[1];
    f32x4* out4        = (f32x4*)d_out;

    const unsigned n_rows  = (unsigned)in_sizes[0];  // 2,097,152
    const unsigned n_quads = n_rows * 8u;            // 16,777,216 float4 slots

    const unsigned spb = 256u * KPT;                 // 2048 slots per block
    const unsigned grid = (n_quads + spb - 1) / spb; // 8192

    if (n_quads % spb == 0) {
        hoo_kernel<false><<<grid, 256, 0, stream>>>(x, omega, out4, n_quads);
    } else {
        hoo_kernel<true><<<grid, 256, 0, stream>>>(x, omega, out4, n_quads);
    }
}

// Round 8
// 47.473 us; speedup vs baseline: 1.6148x; 1.6148x over previous
//
#include <hip/hip_runtime.h>
#include <hip/hip_bf16.h>

// HarmonicOscillatorOrbitals: out[b,i,j] = exp(-s^2/2) * H_j(s), s = x[b,i]*k
// x: (65536, 32, 1) fp32; out: (65536, 32, 32) fp32 (= 16,777,216 float4 slots).
//
// Structure = round 6 (best: 50.4 us, 5.49 TB/s): 8 LOCKSTEP chains per
// thread — the single divergent loop advances all 8 chains together, giving
// 8-way FMA ILP. (Round 7's per-chain restructure serialized the chains:
// 76.7 us. ILP across chains is load-bearing; do not restructure.)
//
// Thread layout: slot f = blockIdx.x*2048 + kk*256 + tid, row = f>>3,
// quad = tid&7 (invariant across kk). Every store wave-contiguous (1 KB).
// This round vs R6 (memory pattern byte-identical):
//   1. GUARD templated out — grid divides n_quads exactly, so zero bounds
//      compares/branches in the hot variant.
//   2. expf -> __expf (v_exp_f32; tolerance is ~bf16-level, huge headroom).

#define KPT 8  // float4 slots per thread

typedef float f32x4 __attribute__((ext_vector_type(4)));

template <bool GUARD>
__global__ __launch_bounds__(256) void hoo_kernel(
    const float* __restrict__ x,
    const float* __restrict__ omega,
    f32x4* __restrict__ out4,
    unsigned n_quads)
{
    const unsigned tid  = threadIdx.x;
    const unsigned quad = tid & 7;  // same for all KPT slots (256 % 8 == 0)
    const unsigned base = blockIdx.x * (256u * KPT) + tid;

    const float k = omega[0];

    float env[KPT], twox[KPT];
    float h0[KPT], h1[KPT], h2[KPT], h3[KPT];

#pragma unroll
    for (int kk = 0; kk < KPT; ++kk) {
        const unsigned f   = base + (unsigned)kk * 256u;
        const unsigned row = (GUARD ? (f < n_quads ? f : n_quads - 1u) : f) >> 3;
        const float s = x[row] * k;
        env[kk]  = __expf(-0.5f * (s * s));
        const float tx = 2.0f * s;
        twox[kk] = tx;
        // H_0=1, H_1=2x, H_2, H_3
        h0[kk] = 1.0f;
        h1[kk] = tx;
        h2[kk] = tx * h1[kk] - 2.0f;
        h3[kk] = tx * h2[kk] - 4.0f * h1[kk];
    }

    // Advance all 8 chains 4 Hermite orders per iteration, in lockstep;
    // trip count = quad (divergent across lanes only). 8-way FMA ILP.
    float c = 6.0f;  // 2*(k-1) for k=4
    for (unsigned it = 0; it < quad; ++it) {
        const float c1 = c + 2.0f;
        const float c2 = c + 4.0f;
        const float c3 = c + 6.0f;
#pragma unroll
        for (int kk = 0; kk < KPT; ++kk) {
            const float tx = twox[kk];
            const float n0 = tx * h3[kk] - c  * h2[kk];
            const float n1 = tx * n0     - c1 * h3[kk];
            const float n2 = tx * n1     - c2 * n0;
            const float n3 = tx * n2     - c3 * n1;
            h0[kk] = n0; h1[kk] = n1; h2[kk] = n2; h3[kk] = n3;
        }
        c += 8.0f;
    }

#pragma unroll
    for (int kk = 0; kk < KPT; ++kk) {
        const unsigned f = base + (unsigned)kk * 256u;
        if (!GUARD || f < n_quads) {
            f32x4 v;
            v.x = env[kk] * h0[kk];
            v.y = env[kk] * h1[kk];
            v.z = env[kk] * h2[kk];
            v.w = env[kk] * h3[kk];
            out4[f] = v;
        }
    }
}

extern "C" void kernel_launch(void* const* d_in, const int* in_sizes, int n_in,
                              void* d_out, int out_size, void* d_ws, size_t ws_size,
                              hipStream_t stream) {
    const float* x     = (const float*)d_in[0];
    const float* omega = (const float*)d_in[1];
    f32x4* out4        = (f32x4*)d_out;

    const unsigned n_rows  = (unsigned)in_sizes[0];  // 2,097,152
    const unsigned n_quads = n_rows * 8u;            // 16,777,216 float4 slots

    const unsigned spb = 256u * KPT;                 // 2048 slots per block
    const unsigned grid = (n_quads + spb - 1) / spb; // 8192

    if (n_quads % spb == 0) {
        hoo_kernel<false><<<grid, 256, 0, stream>>>(x, omega, out4, n_quads);
    } else {
        hoo_kernel<true><<<grid, 256, 0, stream>>>(x, omega, out4, n_quads);
    }
}